// Round 11
// baseline (27.663 us; speedup 1.0000x reference)
//
#include <hip/hip_runtime.h>
#include <hip/hip_bf16.h>

// Polyphase resampler, up=2/down=3, 128-tap FIR, via bf16 MFMA.
//   out[2g]   = 2 * sum_u W_g[u]   * fe_r[u],  W_g[k]=x[3g-32+k]
//   out[2g+1] = 2 * sum_u W_g[u+2] * fo_r[u]
// MFMA 16x16x32 bf16, K=96; D[i][j] = out[2g0+16i+j].
//
// R11: R6 macro-structure (best family: 17.9-18.2), ONE change: stage phase
// is pure DMA (global_load_lds width-16 of RAW f32 -> zero VALU, no
// load->cvt->ds_write dependency chain); bf16 cvt moves to compute phase
// where VALU is ~85% idle. LDS 25KB/block (6 blocks/CU). A-window reads are
// 6x ds_read_b128 f32 (4-way conflict ~ 1.58x, LDS off critical path).

typedef __bf16 bf16x8 __attribute__((ext_vector_type(8)));
typedef float  f32x4  __attribute__((ext_vector_type(4)));

constexpr int BT  = 256;            // 4 waves
constexpr int GPB = 2048;           // output pairs (g) per block
constexpr int UPW = GPB / 128 / 4;  // 128-pair MFMA units per wave (= 4)
constexpr int XT  = 3 * GPB + 96;   // 6240 staged f32 x-elements
constexpr int XT4 = XT / 4;         // 1560 float4 groups (6*256 + 24)

__device__ __forceinline__ void gload_lds16(const float* g, float* l) {
    __builtin_amdgcn_global_load_lds(
        (const __attribute__((address_space(1))) void*)g,
        (__attribute__((address_space(3))) void*)l, 16, 0, 0);
}

__device__ __forceinline__ bf16x8 cvt8(float4 a, float4 b) {
    union { bf16x8 v; __hip_bfloat162 h[4]; } u;
    u.h[0] = __float22bfloat162_rn(make_float2(a.x, a.y));
    u.h[1] = __float22bfloat162_rn(make_float2(a.z, a.w));
    u.h[2] = __float22bfloat162_rn(make_float2(b.x, b.y));
    u.h[3] = __float22bfloat162_rn(make_float2(b.z, b.w));
    return u.v;
}

__global__ __launch_bounds__(BT) void resample23_mfma(
    const float* __restrict__ x,
    const float* __restrict__ filt,
    float* __restrict__ out,
    int N, int out_size)
{
    __shared__ __align__(16) float xs[XT];   // raw f32 x tile (24960 B)

    const int t = threadIdx.x;
    const int w = t >> 6;
    const int l = t & 63;
    const int j = l & 15;
    const int q = l >> 4;
    const int G0 = blockIdx.x * GPB;
    const long F0 = 3L * G0 - 32;            // global f32 idx of xs[0]

    // ---- stage x tile ----
    const bool interior = (F0 >= 0) && (F0 + XT <= (long)N);
    if (interior) {
        // pure DMA: 6 full rounds of global_load_lds dwordx4 (zero VALU)
        #pragma unroll
        for (int r = 0; r < 6; ++r) {
            const int fo = 4 * (256 * r + t);         // f32 offset; lane*16B ok
            gload_lds16(x + F0 + fo, xs + fo);
        }
        // 24-float4 tail via plain LDS write
        if (t < 24) {
            float4 v = *reinterpret_cast<const float4*>(x + F0 + 4 * (1536 + t));
            *reinterpret_cast<float4*>(xs + 4 * (1536 + t)) = v;
        }
    } else {
        // boundary blocks (first/last): guarded scalar fill
        for (int r = 0; r < (XT + BT - 1) / BT; ++r) {
            int idx = 256 * r + t;
            if (idx < XT) {
                long gi = F0 + idx;
                xs[idx] = (gi >= 0 && gi < (long)N) ? x[gi] : 0.0f;
            }
        }
    }

    // ---- B fragments (VALU + filter loads run under staging DMA) ----
    const int kq = q * 8, dlt = j >> 1, ph = j & 1;
    bf16x8 Bf[3];
    #pragma unroll
    for (int kc = 0; kc < 3; ++kc) {
        #pragma unroll
        for (int e = 0; e < 8; ++e) {
            int k = 32 * kc + kq + e;
            int v = k - 3 * dlt - 2 * ph;            // tap index u
            float fv = (v >= 0 && v < 64) ? filt[(ph ? 126 : 127) - 2 * v] : 0.0f;
            Bf[kc][e] = (__bf16)fv;
        }
    }

    __syncthreads();   // compiler emits vmcnt(0)+lgkmcnt(0) drain before barrier

    // ---- compute: per unit 6x ds_read_b128 f32, cvt->bf16, 3 MFMA, 4 stores
    #pragma unroll
    for (int s = 0; s < UPW; ++s) {
        const int u  = UPW * w + s;                  // 128-pair unit (0..15)
        const float* bp = xs + 384 * u + 24 * j + 8 * q;

        bf16x8 A0 = cvt8(*(const float4*)(bp +  0), *(const float4*)(bp +  4));
        bf16x8 A1 = cvt8(*(const float4*)(bp + 32), *(const float4*)(bp + 36));
        bf16x8 A2 = cvt8(*(const float4*)(bp + 64), *(const float4*)(bp + 68));

        f32x4 acc = {0.0f, 0.0f, 0.0f, 0.0f};
        acc = __builtin_amdgcn_mfma_f32_16x16x32_bf16(A0, Bf[0], acc, 0, 0, 0);
        acc = __builtin_amdgcn_mfma_f32_16x16x32_bf16(A1, Bf[1], acc, 0, 0, 0);
        acc = __builtin_amdgcn_mfma_f32_16x16x32_bf16(A2, Bf[2], acc, 0, 0, 0);

        // D[i][j]: col=j, row=4q+r  ->  out[2*(G0+128u) + 16*(4q+r) + j]
        const int obase = 2 * (G0 + 128 * u) + 64 * q + j;
        #pragma unroll
        for (int r = 0; r < 4; ++r) {
            int o = obase + 16 * r;
            if (o < out_size) out[o] = 2.0f * acc[r];
        }
    }
}

extern "C" void kernel_launch(void* const* d_in, const int* in_sizes, int n_in,
                              void* d_out, int out_size, void* d_ws, size_t ws_size,
                              hipStream_t stream)
{
    const float* x    = (const float*)d_in[0];
    const float* filt = (const float*)d_in[1];
    float* out        = (float*)d_out;
    const int N       = in_sizes[0];

    const int n_pairs = (out_size + 1) / 2;
    const int blocks  = (n_pairs + GPB - 1) / GPB;
    resample23_mfma<<<blocks, BT, 0, stream>>>(x, filt, out, N, out_size);
}

// Round 12
// 17.709 us; speedup vs baseline: 1.5621x; 1.5621x over previous
//
#include <hip/hip_runtime.h>
#include <hip/hip_bf16.h>

// Polyphase resampler, up=2/down=3, 128-tap FIR, via bf16 MFMA.
//   out[2g]   = 2 * sum_m x[31+3g-m] * f[2m+1]
//   out[2g+1] = 2 * sum_m x[33+3g-m] * f[2m]
// W_g[k] = x[3g-32+k]; fe_r[u]=f[127-2u], fo_r[u]=f[126-2u]:
//   out[2g]   = 2 * sum_u W_g[u]   * fe_r[u]
//   out[2g+1] = 2 * sum_u W_g[u+2] * fo_r[u]
// MFMA 16x16x32 bf16, K=96: A[i][k] = x[3(g0+8i)-32+k] (im2col from LDS),
// B[k][2d+ph] = (ph? fo_r : fe_r)[k-3d-2ph]  =>  D[i][j] = out[2g0+16i+j].
//
// R12: pure revert to R4 — the measured best (17.9 us). Variants tried and
// all slower: persistent+dbuf 26.4, pre-kernel B 20.5, GPB 2048 18.2 (flat),
// barrier-free vmcnt pipeline 24.5, wave-one-shot 27.0, pure-DMA stage 27.7.
// R7 diagnostic: VALU 14%, MFMA 3%, LDS-conflict ~0, eff BW ~4.6 TB/s for
// this dispatch + ~5.7 us fixed replay constant => at practical floor.

typedef __bf16 bf16x8 __attribute__((ext_vector_type(8)));
typedef float  f32x4  __attribute__((ext_vector_type(4)));

constexpr int BT  = 256;            // 4 waves
constexpr int GPB = 4096;           // output pairs (g) per block
constexpr int XT  = 3 * GPB + 96;   // 12384 staged bf16 x-elements
constexpr int XT4 = XT / 4;         // 3096 float4 groups

__global__ __launch_bounds__(BT) void resample23_mfma(
    const float* __restrict__ x,
    const float* __restrict__ filt,
    float* __restrict__ out,
    int N, int out_size)
{
    __shared__ __align__(16) unsigned short xs[XT];   // bf16 x tile

    const int t = threadIdx.x;
    const int w = t >> 6;
    const int l = t & 63;
    const int G0 = blockIdx.x * GPB;
    const long F0 = 3L * G0 - 32;     // global float idx of xs[0]

    // ---- stage x tile: f32 global -> bf16 LDS (coalesced float4) ----
    const bool interior = (F0 >= 0) && (F0 + XT <= (long)N);
    #pragma unroll
    for (int r = 0; r < (XT4 + BT - 1) / BT; ++r) {
        int idx = t + BT * r;
        if (idx < XT4) {
            long f0 = F0 + 4L * idx;
            float4 v;
            if (interior) {
                v = *reinterpret_cast<const float4*>(x + f0);
            } else {
                v.x = (f0 + 0 >= 0 && f0 + 0 < N) ? x[f0 + 0] : 0.0f;
                v.y = (f0 + 1 >= 0 && f0 + 1 < N) ? x[f0 + 1] : 0.0f;
                v.z = (f0 + 2 >= 0 && f0 + 2 < N) ? x[f0 + 2] : 0.0f;
                v.w = (f0 + 3 >= 0 && f0 + 3 < N) ? x[f0 + 3] : 0.0f;
            }
            __hip_bfloat162 p0 = __float22bfloat162_rn(make_float2(v.x, v.y));
            __hip_bfloat162 p1 = __float22bfloat162_rn(make_float2(v.z, v.w));
            *reinterpret_cast<__hip_bfloat162*>(&xs[4 * idx + 0]) = p0;
            *reinterpret_cast<__hip_bfloat162*>(&xs[4 * idx + 2]) = p1;
        }
    }

    // ---- build B fragments (once): lane l -> col j=l&15, k=8*(l>>4)+e ----
    const int j   = l & 15;
    const int kq  = (l >> 4) * 8;
    const int dlt = j >> 1;
    const int ph  = j & 1;
    bf16x8 Bf[3];
    #pragma unroll
    for (int kc = 0; kc < 3; ++kc) {
        #pragma unroll
        for (int e = 0; e < 8; ++e) {
            int k = 32 * kc + kq + e;
            int v = k - 3 * dlt - 2 * ph;           // tap index u
            float fv = (v >= 0 && v < 64) ? filt[(ph ? 126 : 127) - 2 * v] : 0.0f;
            Bf[kc][e] = (__bf16)fv;
        }
    }

    __syncthreads();

    // ---- 8 MFMA-triples per wave: 256 contiguous outputs each ----
    const char* xsb = reinterpret_cast<const char*>(xs);
    #pragma unroll
    for (int s = 0; s < 8; ++s) {
        const int g0   = G0 + 128 * (8 * w + s);        // local c00 = 384*(8w+s)
        const int boff = 768 * (8 * w + s) + 48 * (l & 15) + 16 * (l >> 4);

        f32x4 acc = {0.0f, 0.0f, 0.0f, 0.0f};
        #pragma unroll
        for (int kc = 0; kc < 3; ++kc) {
            bf16x8 a = *reinterpret_cast<const bf16x8*>(xsb + boff + 64 * kc);
            acc = __builtin_amdgcn_mfma_f32_16x16x32_bf16(a, Bf[kc], acc, 0, 0, 0);
        }

        // D[i][j]: col=l&15, row=4*(l>>4)+r  ->  out[2*g0 + 16*row + col]
        const int obase = 2 * g0 + 16 * (4 * (l >> 4)) + j;
        #pragma unroll
        for (int r = 0; r < 4; ++r) {
            int o = obase + 16 * r;
            if (o < out_size) out[o] = 2.0f * acc[r];
        }
    }
}

extern "C" void kernel_launch(void* const* d_in, const int* in_sizes, int n_in,
                              void* d_out, int out_size, void* d_ws, size_t ws_size,
                              hipStream_t stream)
{
    const float* x    = (const float*)d_in[0];
    const float* filt = (const float*)d_in[1];
    float* out        = (float*)d_out;
    const int N       = in_sizes[0];

    const int n_pairs = (out_size + 1) / 2;
    const int blocks  = (n_pairs + GPB - 1) / GPB;
    resample23_mfma<<<blocks, BT, 0, stream>>>(x, filt, out, N, out_size);
}